// Round 1
// baseline (1000.868 us; speedup 1.0000x reference)
//
#include <hip/hip_runtime.h>
#include <stdint.h>

#define B_   8
#define T_   2048
#define D_   1024
#define DFF_ 4096
#define M_   (B_ * T_)   // 16384

typedef __bf16 bf16;
typedef bf16  bf16x8 __attribute__((ext_vector_type(8)));
typedef bf16  bf16x4 __attribute__((ext_vector_type(4)));
typedef float f32x4  __attribute__((ext_vector_type(4)));

#define CAST_LDS(p) ((__attribute__((address_space(3))) void*)(p))
#define CAST_GLB(p) ((const __attribute__((address_space(1))) void*)(p))

// ---------------------------------------------------------------------------
// Weight converts.
// cvt_cat: fp32 -> bf16 with 128-row interleave: dst row nt*256+r  =
//   (r<128 ? W1[nt*128+r] : W2[nt*128+r-128]).  Turns each dual-GEMM into a
//   single GEMM over N_cat = 2N whose 256-wide N-tile holds matching W1/W2
//   column groups (epilogue pairs them via LDS exchange).
// ---------------------------------------------------------------------------
struct CatArgs {
    const float* w1[3];
    const float* w2[3];
    bf16* dst[3];
    int end[3];   // cumulative block ends: {2048, 4096, 12288}
};

__global__ __launch_bounds__(256) void cvt_cat_kernel(CatArgs a) {
    const int b = blockIdx.x;
    const int seg = (b >= a.end[0] ? 1 : 0) + (b >= a.end[1] ? 1 : 0);
    const int d = b - (seg ? a.end[seg - 1] : 0);
    const int nt = d >> 8;
    const int r = d & 255;
    const float* src = ((r < 128) ? a.w1[seg] : a.w2[seg]) +
                       (size_t)((nt << 7) + (r & 127)) * D_;
    bf16* dst = a.dst[seg] + (size_t)d * D_;
    const int t = threadIdx.x;
    const float4 v = ((const float4*)src)[t];
    bf16x4 o;
    o[0] = (bf16)v.x; o[1] = (bf16)v.y; o[2] = (bf16)v.z; o[3] = (bf16)v.w;
    ((bf16x4*)dst)[t] = o;
}

__global__ __launch_bounds__(256) void cvt_plain_kernel(const float* __restrict__ s,
                                                        bf16* __restrict__ d) {
    const int i = (blockIdx.x * 256 + threadIdx.x) * 4;
    const float4 v = *(const float4*)(s + i);
    bf16x4 o;
    o[0] = (bf16)v.x; o[1] = (bf16)v.y; o[2] = (bf16)v.z; o[3] = (bf16)v.w;
    *(bf16x4*)(d + i) = o;
}

// ---------------------------------------------------------------------------
// RMSNorm fp32-in (one block per row, D=1024, 256 threads x float4) -> bf16
// ---------------------------------------------------------------------------
__global__ __launch_bounds__(256) void rmsnorm_kernel(const float* __restrict__ x,
                                                      const float* __restrict__ w,
                                                      bf16* __restrict__ y) {
    const size_t row = blockIdx.x;
    const int t = threadIdx.x;
    const float4 v = ((const float4*)(x + row * D_))[t];
    float ss = v.x * v.x + v.y * v.y + v.z * v.z + v.w * v.w;
#pragma unroll
    for (int off = 32; off; off >>= 1) ss += __shfl_down(ss, off);
    __shared__ float red[4];
    if ((t & 63) == 0) red[t >> 6] = ss;
    __syncthreads();
    const float total = red[0] + red[1] + red[2] + red[3];
    const float rstd = rsqrtf(total * (1.0f / (float)D_) + 1e-6f);
    const float4 wv = ((const float4*)w)[t];
    bf16x4 o;
    o[0] = (bf16)(v.x * rstd * wv.x);
    o[1] = (bf16)(v.y * rstd * wv.y);
    o[2] = (bf16)(v.z * rstd * wv.z);
    o[3] = (bf16)(v.w * rstd * wv.w);
    ((bf16x4*)(y + row * D_))[t] = o;
}

// ---------------------------------------------------------------------------
// RMSNorm bf16-in (x1 path) -> bf16 out
// ---------------------------------------------------------------------------
__global__ __launch_bounds__(256) void rmsnorm_bf_kernel(const bf16* __restrict__ x,
                                                         const float* __restrict__ w,
                                                         bf16* __restrict__ y) {
    const size_t row = blockIdx.x;
    const int t = threadIdx.x;
    const bf16x4 xv = ((const bf16x4*)(x + row * D_))[t];
    float f0 = (float)xv[0], f1 = (float)xv[1], f2 = (float)xv[2], f3 = (float)xv[3];
    float ss = f0 * f0 + f1 * f1 + f2 * f2 + f3 * f3;
#pragma unroll
    for (int off = 32; off; off >>= 1) ss += __shfl_down(ss, off);
    __shared__ float red[4];
    if ((t & 63) == 0) red[t >> 6] = ss;
    __syncthreads();
    const float total = red[0] + red[1] + red[2] + red[3];
    const float rstd = rsqrtf(total * (1.0f / (float)D_) + 1e-6f);
    const float4 wv = ((const float4*)w)[t];
    bf16x4 o;
    o[0] = (bf16)(f0 * rstd * wv.x);
    o[1] = (bf16)(f1 * rstd * wv.y);
    o[2] = (bf16)(f2 * rstd * wv.z);
    o[3] = (bf16)(f3 * rstd * wv.w);
    ((bf16x4*)(y + row * D_))[t] = o;
}

// ---------------------------------------------------------------------------
// Chunked fused liquid-tanh + PLIF scan (warm-up contraction).
// ---------------------------------------------------------------------------
#define SCAN_C  32
#define SCAN_L  (T_ / SCAN_C)   // 64
#define SCAN_W  32
#define SCAN_PF 8

template <int N, int W0>
__device__ __forceinline__ void scan_body(const uint32_t* __restrict__ p,
                                          bf16* __restrict__ o, const int ts,
                                          const float pdec, const float om,
                                          const float th) {
    uint32_t buf[SCAN_PF];
#pragma unroll
    for (int i = 0; i < SCAN_PF; ++i) buf[i] = p[(size_t)i * D_];
    float h = 0.0f, v = 0.0f;
#pragma unroll 8
    for (int k = 0; k < N; ++k) {
        const uint32_t w = buf[k & (SCAN_PF - 1)];
        if (k + SCAN_PF < N) buf[k & (SCAN_PF - 1)] = p[(size_t)(k + SCAN_PF) * D_];
        const float a  = __builtin_bit_cast(float, w << 16);
        const float bb = __builtin_bit_cast(float, w & 0xffff0000u);
        const float xv = fmaf(a, h, bb);
        const float e2 = __expf(2.0f * xv);
        h = 1.0f - __fdividef(2.0f, 1.0f + e2);          // tanh(xv)
        const float vpre = fmaf(pdec, v, om * h);
        const float s = (vpre > th) ? 1.0f : 0.0f;
        v = vpre - s * th;
        if (k >= W0) o[(size_t)(ts + k) * D_] = (bf16)(s + h);
    }
}

__global__ __launch_bounds__(256) void scan_kernel(const uint32_t* __restrict__ ABp,
                                                   const float* __restrict__ log_tau,
                                                   const float* __restrict__ thr,
                                                   bf16* __restrict__ sp) {
    const int g = blockIdx.x * 256 + threadIdx.x;
    const int d = g & (D_ - 1);
    const int bc = g >> 10;
    const int b = bc / SCAN_C;
    const int c = bc % SCAN_C;
    const float pdec = __expf(-__expf(-log_tau[d]));
    const float om = 1.0f - pdec;
    const float th = thr[d];
    const int t0 = c * SCAN_L;
    const uint32_t* base = ABp + (size_t)b * (T_ * D_) + d;
    bf16* o = sp + (size_t)b * (T_ * D_) + d;
    if (c == 0) {
        scan_body<SCAN_L, 0>(base, o, 0, pdec, om, th);
    } else {
        const int ts = t0 - SCAN_W;
        scan_body<SCAN_L + SCAN_W, SCAN_W>(base + (size_t)ts * D_, o, ts, pdec, om, th);
    }
}

// ---------------------------------------------------------------------------
// 8-phase 256x256 GEMM (plain-HIP port of the verified m201 schedule).
//   C[M, Ncat] = A[M,K] @ Bw[Ncat,K]^T, 8 waves (2M x 4N), per-wave 128x64,
//   BK=64 as two k-half LDS slots of [256 rows][32 cols] bf16 (64B rows).
//   Double-buffered (4 slots/tensor), counted vmcnt(6) once per K-tile,
//   raw s_barriers, setprio(1) around each 16-MFMA cluster.
// LDS swizzle (both-sides, rule #21): global source column pre-permuted
//   (col8 ^= (row>>1)&3), LDS dest linear for global_load_lds, ds_read
//   applies the same XOR (quad ^ (row>>1)&3).
// Stage schedule per tile t (slot liveness verified):
//   ph1 (mh0,k0): stage A-k1(t+1)      ph2 (mh1,k0): stage B-k0(t+2)
//   ph3 (mh0,k1): stage A-k0(t+2)      ph4 (mh1,k1): stage B-k1(t+2) + vmcnt(6)
//   vmcnt(6) at ph4 leaves exactly the 3 newest half-tiles in flight ->
//   all of tile t+1 has landed before its phases read it.
// MODE 0: delta/b  (dual-cat) -> pack bf16(A_t) | bf16(b_t)<<16 -> u32
// MODE 1: syn/gate (dual-cat) -> out = x + syn*sigmoid(gate)  (bf16)
// MODE 2: ffn g/u  (dual-cat) -> out = silu(g)*u              (bf16)
// MODE 3: ffn down (single)   -> out = x1 + acc               (fp32)
// Dual epilogue: W2-side waves (nc>=2) park acc in the dead staging LDS,
// W1-side waves pair (mr,nc) <-> (mr,nc+2) and fuse.
// ---------------------------------------------------------------------------

#define STG_A(tt, kh)                                                                  \
  { bf16* l_ = lA0 + ((((tt) & 1) << 1) + (kh)) * 8192;                                \
    const bf16* g_ = gA + (tt) * 64 + ((kh) << 5);                                     \
    __builtin_amdgcn_global_load_lds(CAST_GLB(g_), CAST_LDS(l_), 16, 0, 0);            \
    __builtin_amdgcn_global_load_lds(CAST_GLB(g_ + g2), CAST_LDS(l_ + 4096), 16, 0, 0); }
#define STG_B(tt, kh)                                                                  \
  { bf16* l_ = lB0 + ((((tt) & 1) << 1) + (kh)) * 8192;                                \
    const bf16* g_ = gB + (tt) * 64 + ((kh) << 5);                                     \
    __builtin_amdgcn_global_load_lds(CAST_GLB(g_), CAST_LDS(l_), 16, 0, 0);            \
    __builtin_amdgcn_global_load_lds(CAST_GLB(g_ + g2), CAST_LDS(l_ + 4096), 16, 0, 0); }
#define DSREAD_A(KS, MH)                                                               \
  { const bf16* As_ = smA + (cb + (KS)) * 8192;                                        \
    _Pragma("unroll")                                                                  \
    for (int i = 0; i < 4; ++i) {                                                      \
      const int row_ = mr128 + (MH) * 64 + i * 16 + lane15;                            \
      af[i] = *(const bf16x8*)(As_ + row_ * 32 + ((quad ^ ((row_ >> 1) & 3)) << 3));   \
    } }
#define DSREAD_B(KS)                                                                   \
  { const bf16* Bs_ = smB + (cb + (KS)) * 8192;                                        \
    _Pragma("unroll")                                                                  \
    for (int j = 0; j < 4; ++j) {                                                      \
      const int row_ = nc64 + j * 16 + lane15;                                         \
      bfr[j] = *(const bf16x8*)(Bs_ + row_ * 32 + ((quad ^ ((row_ >> 1) & 3)) << 3));  \
    } }
#define MFMA16(MH)                                                                     \
  __builtin_amdgcn_s_setprio(1);                                                       \
  _Pragma("unroll")                                                                    \
  for (int i = 0; i < 4; ++i)                                                          \
    _Pragma("unroll")                                                                  \
    for (int j = 0; j < 4; ++j)                                                        \
      acc[(MH) * 4 + i][j] = __builtin_amdgcn_mfma_f32_16x16x32_bf16(                  \
          af[i], bfr[j], acc[(MH) * 4 + i][j], 0, 0, 0);                               \
  __builtin_amdgcn_s_setprio(0);
#define GBAR() __builtin_amdgcn_s_barrier()
#define LGKM0() asm volatile("s_waitcnt lgkmcnt(0)" ::: "memory")

template <int MODE>
__global__ __launch_bounds__(512, 2) void gemm8_kernel(
    const bf16* __restrict__ A, const bf16* __restrict__ Bw,
    const int Ncat, const int K, const int Nlog,
    const float* __restrict__ b1, const float* __restrict__ b2,
    const float* __restrict__ extra, const bf16* __restrict__ extra_bf,
    void* __restrict__ outp) {
    constexpr bool DUAL = (MODE != 3);
    __shared__ bf16 smem[65536] __attribute__((aligned(16)));   // 128 KiB
    bf16* const smA = smem;             // 4 slots x 8192 elems ([256][32] each)
    bf16* const smB = smem + 32768;

    const int tid = threadIdx.x;
    const int wave = tid >> 6;
    const int lane = tid & 63;
    const int lane15 = lane & 15;
    const int quad = lane >> 4;
    const int mr = wave >> 2;          // 0..1
    const int nc = wave & 3;           // 0..3
    const int mr128 = mr * 128;
    const int nc64 = nc * 64;

    // XCD-aware block swizzle (all grids here are divisible by 8)
    int bid = blockIdx.x;
    const int cpx = gridDim.x >> 3;
    bid = (bid & 7) * cpx + (bid >> 3);
    const int NTN = Ncat >> 8;
    const int nt = bid % NTN;
    const int mt = bid / NTN;

    // staging addressing: chunk c = q*512 + tid, row = c>>2, dest linear,
    // source column XOR-swizzled to match the ds_read-side swizzle.
    const int srow = tid >> 2;                               // 0..127 (q=0)
    const int scol = (((tid & 3) ^ ((srow >> 1) & 3)) << 3); // 0/8/16/24 elems
    const bf16* const gA = A + (size_t)(mt * 256 + srow) * K + scol;
    const bf16* const gB = Bw + (size_t)(nt * 256 + srow) * K + scol;
    const size_t g2 = (size_t)128 * K;                       // q=1: rows +128
    bf16* const lA0 = smA + (wave << 9);                     // + slot*8192 later
    bf16* const lB0 = smB + (wave << 9);

    const int NT = K >> 6;

    f32x4 acc[8][4] = {};
    bf16x8 af[4];
    bf16x8 bfr[4];

    // prologue: tile 0 fully + 3 half-tiles of tile 1 (order = steady pattern)
    STG_B(0, 0); STG_A(0, 0); STG_B(0, 1); STG_A(0, 1);
    asm volatile("s_waitcnt vmcnt(4)" ::: "memory");
    STG_B(1, 0); STG_A(1, 0); STG_B(1, 1);
    asm volatile("s_waitcnt vmcnt(6)" ::: "memory");
    GBAR();

    for (int t = 0; t < NT; ++t) {
        const int cb = (t & 1) << 1;   // compute-buffer slot base

        // phase 1: (mh0, k0)
        DSREAD_A(0, 0); DSREAD_B(0);
        if (t + 1 < NT) STG_A(t + 1, 1);
        GBAR(); LGKM0();
        MFMA16(0);
        GBAR();

        // phase 2: (mh1, k0) — B-frags held in regs
        DSREAD_A(0, 1);
        if (t + 2 < NT) STG_B(t + 2, 0);
        GBAR(); LGKM0();
        MFMA16(1);
        GBAR();

        // phase 3: (mh0, k1)
        DSREAD_A(1, 0); DSREAD_B(1);
        if (t + 2 < NT) STG_A(t + 2, 0);
        GBAR(); LGKM0();
        MFMA16(0);
        GBAR();

        // phase 4: (mh1, k1) + counted vmcnt (never 0 in steady state)
        DSREAD_A(1, 1);
        if (t + 2 < NT) {
            STG_B(t + 2, 1);
            asm volatile("s_waitcnt vmcnt(6)" ::: "memory");
        } else {
            asm volatile("s_waitcnt vmcnt(0)" ::: "memory");
        }
        GBAR(); LGKM0();
        MFMA16(1);
        GBAR();
    }

    // ---------------- epilogue ----------------
    if constexpr (DUAL) {
        // W2-side waves park acc in (now dead) staging LDS; W1-side fuses.
        float* const xch = (float*)smem;   // 4 slots x 8192 f32 = 128 KiB
        if (nc >= 2) {
            float* const dst = xch + (mr * 2 + (nc - 2)) * 8192;
#pragma unroll
            for (int i8 = 0; i8 < 8; ++i8)
#pragma unroll
                for (int j = 0; j < 4; ++j)
#pragma unroll
                    for (int r = 0; r < 4; ++r)
                        dst[(i8 * 16 + quad * 4 + r) * 64 + j * 16 + lane15] =
                            acc[i8][j][r];
        }
        __syncthreads();
        if (nc < 2) {
            const float* const src = xch + (mr * 2 + nc) * 8192;
            const int mbase = mt * 256 + mr128;
            const int nbase = nt * 128 + nc64;
#pragma unroll
            for (int i8 = 0; i8 < 8; ++i8)
#pragma unroll
                for (int j = 0; j < 4; ++j)
#pragma unroll
                    for (int r = 0; r < 4; ++r) {
                        const int rl = i8 * 16 + quad * 4 + r;
                        const int cl = j * 16 + lane15;
                        const int m = mbase + rl;
                        const int n = nbase + cl;
                        const size_t idx = (size_t)m * Nlog + n;
                        const float v1 = acc[i8][j][r];
                        const float v2 = src[rl * 64 + cl];
                        if constexpr (MODE == 0) {
                            const float dl = v1 + b1[n];
                            const float spv = (dl > 20.0f) ? dl : log1pf(__expf(dl));
                            const float bv = spv * (v2 + b2[n]);
                            const float av = __expf(-spv * __expf(extra[n]));
                            const uint32_t pa =
                                (uint32_t)__builtin_bit_cast(unsigned short, (bf16)av);
                            const uint32_t pb =
                                (uint32_t)__builtin_bit_cast(unsigned short, (bf16)bv);
                            ((uint32_t*)outp)[idx] = pa | (pb << 16);
                        } else if constexpr (MODE == 1) {
                            const float syn = v1 + b1[n];
                            const float z = v2 + b2[n];
                            const float gate = 1.0f / (1.0f + __expf(-z));
                            ((bf16*)outp)[idx] = (bf16)(extra[idx] + syn * gate);
                        } else {   // MODE 2
                            const float sg = v1 / (1.0f + __expf(-v1));
                            ((bf16*)outp)[idx] = (bf16)(sg * v2);
                        }
                    }
        }
    } else {   // MODE 3: single-B, direct write
        const int mbase = mt * 256 + mr128;
        const int nbase = nt * 256 + nc64;
#pragma unroll
        for (int i8 = 0; i8 < 8; ++i8)
#pragma unroll
            for (int j = 0; j < 4; ++j)
#pragma unroll
                for (int r = 0; r < 4; ++r) {
                    const int m = mbase + i8 * 16 + quad * 4 + r;
                    const int n = nbase + j * 16 + lane15;
                    const size_t idx = (size_t)m * Nlog + n;
                    ((float*)outp)[idx] = (float)extra_bf[idx] + acc[i8][j][r];
                }
    }
}

#undef STG_A
#undef STG_B
#undef DSREAD_A
#undef DSREAD_B
#undef MFMA16
#undef GBAR
#undef LGKM0

// ---------------------------------------------------------------------------
extern "C" void kernel_launch(void* const* d_in, const int* in_sizes, int n_in,
                              void* d_out, int out_size, void* d_ws, size_t ws_size,
                              hipStream_t stream) {
    const float* x        = (const float*)d_in[0];
    const float* rms_w1   = (const float*)d_in[1];
    const float* rms_w2   = (const float*)d_in[2];
    const float* delta_w  = (const float*)d_in[3];
    const float* delta_b  = (const float*)d_in[4];
    const float* b_w      = (const float*)d_in[5];
    const float* b_b      = (const float*)d_in[6];
    const float* A_log    = (const float*)d_in[7];
    const float* log_tau  = (const float*)d_in[8];
    const float* plif_thr = (const float*)d_in[9];
    const float* syn_w    = (const float*)d_in[10];
    const float* syn_b    = (const float*)d_in[11];
    const float* gate_w   = (const float*)d_in[12];
    const float* gate_b   = (const float*)d_in[13];
    const float* ffn_g_w  = (const float*)d_in[14];
    const float* ffn_u_w  = (const float*)d_in[15];
    const float* ffn_d_w  = (const float*)d_in[16];

    char* ws = (char*)d_ws;
    const size_t MB = 1024ull * 1024ull;
    // cat-interleaved bf16 weights: [0,32MB)
    bf16* wcat_db = (bf16*)(ws + 0 * MB);    // [2048,1024]  4MB
    bf16* wcat_sg = (bf16*)(ws + 4 * MB);    // [2048,1024]  4MB
    bf16* wcat_gu = (bf16*)(ws + 8 * MB);    // [8192,1024] 16MB
    bf16* wd      = (bf16*)(ws + 24 * MB);   // [1024,4096]  8MB
    // phase-1 buffers (all dead before act is written):
    bf16*     y1      = (bf16*)(ws + 32 * MB);       // 32MB
    uint32_t* ABp     = (uint32_t*)(ws + 64 * MB);   // 64MB
    bf16*     spikein = (bf16*)(ws + 128 * MB);      // 32MB
    // persistent:
    bf16* x1 = (bf16*)(ws + 160 * MB);               // 32MB
    bf16* y2 = (bf16*)(ws + 224 * MB);               // 32MB
    // act aliases the dead phase-1 region [32MB,160MB): 16384*4096*2 = 128MB
    bf16* act = (bf16*)(ws + 32 * MB);
    float* outF = (float*)d_out;

    // --- weight converts ---
    CatArgs ca;
    ca.w1[0] = delta_w; ca.w2[0] = b_w;     ca.dst[0] = wcat_db;
    ca.w1[1] = syn_w;   ca.w2[1] = gate_w;  ca.dst[1] = wcat_sg;
    ca.w1[2] = ffn_g_w; ca.w2[2] = ffn_u_w; ca.dst[2] = wcat_gu;
    ca.end[0] = 2048; ca.end[1] = 4096; ca.end[2] = 12288;
    cvt_cat_kernel<<<12288, 256, 0, stream>>>(ca);
    cvt_plain_kernel<<<(D_ * DFF_) / 1024, 256, 0, stream>>>(ffn_d_w, wd);

    // --- RMSNorm 1 ---
    rmsnorm_kernel<<<M_, 256, 0, stream>>>(x, rms_w1, y1);

    // --- dual GEMM (cat): delta/b -> packed (A_t, b_t) ---
    gemm8_kernel<0><<<(2048 / 256) * (M_ / 256), 512, 0, stream>>>(
        y1, wcat_db, 2048, D_, D_, delta_b, b_b, A_log, nullptr, ABp);

    // --- chunked fused liquid + PLIF scans ---
    scan_kernel<<<(B_ * SCAN_C * D_) / 256, 256, 0, stream>>>(ABp, log_tau, plif_thr, spikein);

    // --- dual GEMM (cat): syn/gate -> x1 = x + syn*sigmoid(gate) ---
    gemm8_kernel<1><<<(2048 / 256) * (M_ / 256), 512, 0, stream>>>(
        spikein, wcat_sg, 2048, D_, D_, syn_b, gate_b, x, nullptr, x1);

    // --- RMSNorm 2 (bf16 in) ---
    rmsnorm_bf_kernel<<<M_, 256, 0, stream>>>(x1, rms_w2, y2);

    // --- dual GEMM (cat): ffn gate/up -> act = silu(g)*u ---
    gemm8_kernel<2><<<(8192 / 256) * (M_ / 256), 512, 0, stream>>>(
        y2, wcat_gu, 8192, D_, DFF_, nullptr, nullptr, nullptr, nullptr, act);

    // --- GEMM: ffn down + residual -> out ---
    gemm8_kernel<3><<<(1024 / 256) * (M_ / 256), 512, 0, stream>>>(
        act, wd, 1024, DFF_, D_, nullptr, nullptr, nullptr, x1, outF);
}